// Round 1
// baseline (2145.632 us; speedup 1.0000x reference)
//
#include <hip/hip_runtime.h>

// VectorQuantizeLayer forward == nearest-code lookup:
//   h = x @ W^T + b                          [16384, 256]
//   idx[m] = argmax_v (2*h.c_v - |c_v|^2)    (== argmin L2 dist; |h|^2 is row-const)
//   out[m] = table[idx[m]]                   (straight-through collapses to gather)
// All fp32 (no fp32 MFMA on CDNA4; bf16 would risk argmax flips).

#define M_TOTAL 16384
#define K1 768
#define DQ 256
#define NV 8192

#define RPB 64            // rows per block
#define NCH 128           // codes per N-chunk
#define NCHUNKS (NV / NCH) // 64
#define KC 32             // K-chunk (both phases)

#define LDA_H 260         // h tile leading dim (bank spread for 4-row b128 reads)
#define LDA_XS 36
#define LDA_WT 258
#define LDA_BS 36

struct SP0 { float xs[RPB][LDA_XS]; float wt[KC][LDA_WT]; };          // 42,240 B
struct SP2 { float bs[2][NCH][LDA_BS]; };                             // 36,864 B
struct SP3 { float rs[RPB][17]; int ri[RPB][17]; int bidx[RPB]; };    //  9,504 B
union SMem { SP0 p0; SP2 p2; SP3 p3; };

__global__ __launch_bounds__(256) void vq_c2_kernel(const float* __restrict__ table,
                                                    float* __restrict__ c2) {
  const int v = blockIdx.x * 256 + threadIdx.x;
  const float4* row = (const float4*)(table + (size_t)v * DQ);
  float s = 0.f;
#pragma unroll 8
  for (int q = 0; q < DQ / 4; ++q) {
    float4 t = row[q];
    s = fmaf(t.x, t.x, s); s = fmaf(t.y, t.y, s);
    s = fmaf(t.z, t.z, s); s = fmaf(t.w, t.w, s);
  }
  c2[v] = s;
}

__global__ __launch_bounds__(256) void vq_main_kernel(
    const float* __restrict__ x, const float* __restrict__ Wm,
    const float* __restrict__ bias, const float* __restrict__ table,
    const float* __restrict__ c2, float* __restrict__ out) {

  __shared__ float hs[RPB][LDA_H];   // 66,560 B
  __shared__ SMem sm;                // 42,240 B  (total 108.8 KB -> 1 block/CU)

  const int tid = threadIdx.x;
  const int tx = tid & 15;
  const int ty = tid >> 4;
  const int rowbase = blockIdx.x * RPB;

  // ---------------- Phase 0: h tile = x @ W^T + b ----------------
  float acc0[4][16];
#pragma unroll
  for (int i = 0; i < 4; ++i)
#pragma unroll
    for (int j = 0; j < 16; ++j) acc0[i][j] = 0.f;

  const int r_ld = tid >> 2;   // 0..63
  const int s_ld = tid & 3;    // 0..3

  for (int kc = 0; kc < K1 / KC; ++kc) {
    const int k0 = kc * KC;
    float4 xa = *(const float4*)(x + (size_t)(rowbase + r_ld) * K1 + k0 + s_ld * 4);
    float4 xb = *(const float4*)(x + (size_t)(rowbase + r_ld) * K1 + k0 + (s_ld + 4) * 4);
    float4 wv[8];
#pragma unroll
    for (int q = 0; q < 8; ++q)
      wv[q] = *(const float4*)(Wm + (size_t)tid * K1 + k0 + q * 4);
    __syncthreads();   // prior chunk fully consumed
    *(float4*)&sm.p0.xs[r_ld][s_ld * 4] = xa;
    *(float4*)&sm.p0.xs[r_ld][(s_ld + 4) * 4] = xb;
#pragma unroll
    for (int q = 0; q < 8; ++q) {   // transpose W chunk into k-major
      sm.p0.wt[q * 4 + 0][tid] = wv[q].x;
      sm.p0.wt[q * 4 + 1][tid] = wv[q].y;
      sm.p0.wt[q * 4 + 2][tid] = wv[q].z;
      sm.p0.wt[q * 4 + 3][tid] = wv[q].w;
    }
    __syncthreads();
#pragma unroll 4
    for (int k = 0; k < KC; ++k) {
      float a[4];
#pragma unroll
      for (int i = 0; i < 4; ++i) a[i] = sm.p0.xs[ty * 4 + i][k];
#pragma unroll
      for (int j = 0; j < 16; ++j) {
        float w = sm.p0.wt[k][tx + 16 * j];
#pragma unroll
        for (int i = 0; i < 4; ++i) acc0[i][j] = fmaf(a[i], w, acc0[i][j]);
      }
    }
  }
#pragma unroll
  for (int j = 0; j < 16; ++j) {
    float bj = bias[tx + 16 * j];
#pragma unroll
    for (int i = 0; i < 4; ++i)
      hs[ty * 4 + i][tx + 16 * j] = acc0[i][j] + bj;
  }
  __syncthreads();

  // ---------------- Phase 2: score scan + argmax ----------------
  float best[4];
  int bidx[4];
#pragma unroll
  for (int i = 0; i < 4; ++i) { best[i] = -3.4e38f; bidx[i] = 0; }

  const int c_ld = tid >> 1;          // 0..127 code within chunk
  const int ks_ld = (tid & 1) * 16;   // float offset within 32-k chunk

  float4 breg[4];
  {
    const float* src = table + (size_t)c_ld * DQ + ks_ld;   // chunk 0: nc=0,kc=0
#pragma unroll
    for (int q = 0; q < 4; ++q) breg[q] = *(const float4*)(src + q * 4);
  }

  float acc[4][8];

  for (int ci = 0; ci < NCHUNKS * 8; ++ci) {
    const int cur = ci & 1;
    const int kc = ci & 7;
    const int nc = ci >> 3;
    if (kc == 0) {
#pragma unroll
      for (int i = 0; i < 4; ++i)
#pragma unroll
        for (int j = 0; j < 8; ++j) acc[i][j] = 0.f;
    }
    __syncthreads();   // (a) everyone done reading bs[cur] (iter ci-2)
#pragma unroll
    for (int q = 0; q < 4; ++q)
      *(float4*)&sm.p2.bs[cur][c_ld][ks_ld + q * 4] = breg[q];
    if (ci + 1 < NCHUNKS * 8) {   // prefetch next chunk; hidden under compute below
      const int nc2 = (ci + 1) >> 3, kc2 = (ci + 1) & 7;
      const float* src = table + (size_t)(nc2 * NCH + c_ld) * DQ + kc2 * KC + ks_ld;
#pragma unroll
      for (int q = 0; q < 4; ++q) breg[q] = *(const float4*)(src + q * 4);
    }
    __syncthreads();   // (b) bs[cur] ready
#pragma unroll
    for (int k4 = 0; k4 < 8; ++k4) {
      float4 a4[4];
      float4 b4[8];
#pragma unroll
      for (int i = 0; i < 4; ++i)
        a4[i] = *(const float4*)&hs[ty * 4 + i][kc * KC + k4 * 4];
#pragma unroll
      for (int j = 0; j < 8; ++j)
        b4[j] = *(const float4*)&sm.p2.bs[cur][tx + 16 * j][k4 * 4];
#pragma unroll
      for (int i = 0; i < 4; ++i)
#pragma unroll
        for (int j = 0; j < 8; ++j) {
          acc[i][j] = fmaf(a4[i].x, b4[j].x, acc[i][j]);
          acc[i][j] = fmaf(a4[i].y, b4[j].y, acc[i][j]);
          acc[i][j] = fmaf(a4[i].z, b4[j].z, acc[i][j]);
          acc[i][j] = fmaf(a4[i].w, b4[j].w, acc[i][j]);
        }
    }
    if (kc == 7) {   // full K accumulated for this 128-code chunk
#pragma unroll
      for (int j = 0; j < 8; ++j) {
        const int code = nc * NCH + tx + 16 * j;
        const float cc = c2[code];
#pragma unroll
        for (int i = 0; i < 4; ++i) {
          const float s = fmaf(2.f, acc[i][j], -cc);
          if (s > best[i]) { best[i] = s; bidx[i] = code; }   // strict > : first max wins
        }
      }
    }
  }

  // ---------------- argmax reduce across the 16 tx lanes sharing a row ----------------
  __syncthreads();   // done with sm.p2
#pragma unroll
  for (int i = 0; i < 4; ++i) {
    sm.p3.rs[ty * 4 + i][tx] = best[i];
    sm.p3.ri[ty * 4 + i][tx] = bidx[i];
  }
  __syncthreads();
  if (tid < RPB) {
    float bsc = sm.p3.rs[tid][0];
    int bix = sm.p3.ri[tid][0];
    for (int t = 1; t < 16; ++t) {
      float s = sm.p3.rs[tid][t];
      int ix = sm.p3.ri[tid][t];
      if (s > bsc || (s == bsc && ix < bix)) { bsc = s; bix = ix; }
    }
    sm.p3.bidx[tid] = bix;
  }
  __syncthreads();

  // ---------------- gather: out[row] = table[best] ----------------
  {
    const int row = tid >> 2;
    const int part = tid & 3;
    const int code = sm.p3.bidx[row];
    const float4* src = (const float4*)(table + (size_t)code * DQ + part * 64);
    float4* dst = (float4*)(out + (size_t)(rowbase + row) * DQ + part * 64);
#pragma unroll
    for (int q = 0; q < 16; ++q) dst[q] = src[q];
  }
}

extern "C" void kernel_launch(void* const* d_in, const int* in_sizes, int n_in,
                              void* d_out, int out_size, void* d_ws, size_t ws_size,
                              hipStream_t stream) {
  const float* x     = (const float*)d_in[0];
  const float* Wm    = (const float*)d_in[1];
  const float* bias  = (const float*)d_in[2];
  const float* table = (const float*)d_in[3];
  float* out = (float*)d_out;
  float* c2 = (float*)d_ws;   // 8192 floats = 32 KB scratch

  vq_c2_kernel<<<NV / 256, 256, 0, stream>>>(table, c2);
  vq_main_kernel<<<M_TOTAL / RPB, 256, 0, stream>>>(x, Wm, bias, table, c2, out);
}